// Round 2
// baseline (1598.366 us; speedup 1.0000x reference)
//
#include <hip/hip_runtime.h>
#include <hip/hip_bf16.h>
#include <stdint.h>

typedef unsigned int uint;

#define NNODES 100000
#define NEDGES 1600000
#define RCONST 400
#define NPB 8   // nodes per block in the fused layer kernel

// ---------------- CSR build ----------------

__global__ __launch_bounds__(256) void deg_kernel(const int* __restrict__ edges,
                                                  int* __restrict__ deg, int E) {
    int e = blockIdx.x * 256 + threadIdx.x;
    if (e < E) atomicAdd(&deg[edges[e * 3 + 2]], 1);
}

__global__ __launch_bounds__(1024) void scan_kernel(const int* __restrict__ deg,
                                                    int* __restrict__ rowstart, int N) {
    __shared__ int tmp[1024];
    int t = threadIdx.x;
    int offset = 0;
    int nChunks = (N + 1023) >> 10;
    for (int c = 0; c < nChunks; ++c) {
        int i = (c << 10) + t;
        int v = (i < N) ? deg[i] : 0;
        tmp[t] = v;
        __syncthreads();
        for (int s = 1; s < 1024; s <<= 1) {
            int a = (t >= s) ? tmp[t - s] : 0;
            __syncthreads();
            tmp[t] += a;
            __syncthreads();
        }
        int incl = tmp[t];
        if (i < N) rowstart[i] = offset + incl - v;  // exclusive scan
        int total = tmp[1023];
        __syncthreads();
        offset += total;
    }
    if (t == 0) rowstart[N] = offset;
}

__global__ __launch_bounds__(256) void fill_kernel(const int* __restrict__ edges,
                                                   const int* __restrict__ rowstart,
                                                   int* __restrict__ fill,
                                                   int* __restrict__ elist, int E) {
    int e = blockIdx.x * 256 + threadIdx.x;
    if (e < E) {
        int src = edges[e * 3];
        int rel = edges[e * 3 + 1];
        int dst = edges[e * 3 + 2];
        int bkt = (rel >= RCONST) + (rel >= 2 * RCONST);
        int pos = rowstart[dst] + atomicAdd(&fill[dst], 1);
        elist[pos] = src | (bkt << 17);   // src < 2^17, bucket in [0,3)
    }
}

// ---------------- fused layer ----------------
// For each node d:  S_r = sum_{e: dst=d, bkt=r} x[src_e]  (gather, no atomics)
//   m = (W[r] @ S_r summed over r + sum_r cnt_r * b[r]) / max(cnt,1)
//   v = relu(m) + Ws @ x[d] + bs
//   out = layernorm(v) * g + be

__global__ __launch_bounds__(128) void layer_kernel(
    const float* __restrict__ x, const int* __restrict__ rowstart,
    const int* __restrict__ elist,
    const float* __restrict__ W,  const float* __restrict__ b,
    const float* __restrict__ Ws, const float* __restrict__ bs,
    const float* __restrict__ g,  const float* __restrict__ be,
    float* __restrict__ y) {
    __shared__ float sS[NPB][3][128];
    __shared__ float sX[NPB][128];
    __shared__ float sCnt[NPB][3];
    __shared__ float sRed[2][NPB][2];

    int o = threadIdx.x;        // output channel 0..127
    int lane = o & 63, wid = o >> 6;
    int n0 = blockIdx.x * NPB;

    // ---- gather/aggregate phase ----
    for (int n = 0; n < NPB; ++n) {
        int node = n0 + n;
        int beg = rowstart[node], end = rowstart[node + 1];
        float a0 = 0.f, a1 = 0.f, a2 = 0.f;
        int c0 = 0, c1 = 0, c2 = 0;
        #pragma unroll 4
        for (int e = beg; e < end; ++e) {
            int p = elist[e];               // block-uniform broadcast load
            int s = p & 0x1FFFF;
            int bkt = p >> 17;
            float xv = x[(size_t)s * 128 + o];
            if (bkt == 0)      { a0 += xv; ++c0; }
            else if (bkt == 1) { a1 += xv; ++c1; }
            else               { a2 += xv; ++c2; }
        }
        sS[n][0][o] = a0; sS[n][1][o] = a1; sS[n][2][o] = a2;
        sX[n][o] = x[(size_t)node * 128 + o];
        if (o == 0) { sCnt[n][0] = (float)c0; sCnt[n][1] = (float)c1; sCnt[n][2] = (float)c2; }
    }
    __syncthreads();

    // ---- matvec phase: thread o computes output channel o for all NPB nodes ----
    float acc[NPB], accS[NPB];
    #pragma unroll
    for (int n = 0; n < NPB; ++n) { acc[n] = 0.f; accS[n] = 0.f; }

    for (int r = 0; r < 3; ++r) {
        const float4* Wrow = (const float4*)(W + ((size_t)(r * 128 + o)) * 128);
        #pragma unroll 8
        for (int kc = 0; kc < 32; ++kc) {
            float4 wq = Wrow[kc];
            int k = kc * 4;
            #pragma unroll
            for (int n = 0; n < NPB; ++n) {
                const float4 A = *(const float4*)&sS[n][r][k];
                acc[n] += wq.x * A.x + wq.y * A.y + wq.z * A.z + wq.w * A.w;
            }
        }
    }
    {
        const float4* Wrow = (const float4*)(Ws + (size_t)o * 128);
        #pragma unroll 8
        for (int kc = 0; kc < 32; ++kc) {
            float4 wq = Wrow[kc];
            int k = kc * 4;
            #pragma unroll
            for (int n = 0; n < NPB; ++n) {
                const float4 A = *(const float4*)&sX[n][k];
                accS[n] += wq.x * A.x + wq.y * A.y + wq.z * A.z + wq.w * A.w;
            }
        }
    }

    float bv0 = b[o], bv1 = b[128 + o], bv2 = b[256 + o];
    float bsv = bs[o], gv = g[o], bev = be[o];

    // ---- epilogue: bias, mean, relu, skip, layernorm ----
    #pragma unroll
    for (int n = 0; n < NPB; ++n) {
        float c0 = sCnt[n][0], c1 = sCnt[n][1], c2 = sCnt[n][2];
        float cnt = c0 + c1 + c2;
        float inv = 1.0f / fmaxf(cnt, 1.0f);
        float m = (acc[n] + c0 * bv0 + c1 * bv1 + c2 * bv2) * inv;
        float v = fmaxf(m, 0.0f) + accS[n] + bsv;

        float s1 = v, s2 = v * v;
        #pragma unroll
        for (int off = 32; off > 0; off >>= 1) {
            s1 += __shfl_down(s1, off, 64);
            s2 += __shfl_down(s2, off, 64);
        }
        if (lane == 0) { sRed[wid][n][0] = s1; sRed[wid][n][1] = s2; }
        __syncthreads();
        float S1 = sRed[0][n][0] + sRed[1][n][0];
        float S2 = sRed[0][n][1] + sRed[1][n][1];
        float mean = S1 * (1.0f / 128.0f);
        float var = S2 * (1.0f / 128.0f) - mean * mean;
        float rstd = rsqrtf(var + 1e-5f);
        float outv = (v - mean) * rstd * gv + bev;
        y[(size_t)(n0 + n) * 128 + o] = outv;
    }
}

// ---------------- launch ----------------

extern "C" void kernel_launch(void* const* d_in, const int* in_sizes, int n_in,
                              void* d_out, int out_size, void* d_ws, size_t ws_size,
                              hipStream_t stream) {
    (void)in_sizes; (void)n_in; (void)out_size; (void)ws_size;

    const int*   edges = (const int*)d_in[0];
    const float* xemb  = (const float*)d_in[1];
    const float* W1  = (const float*)d_in[2];
    const float* b1  = (const float*)d_in[3];
    const float* Ws1 = (const float*)d_in[4];
    const float* bs1 = (const float*)d_in[5];
    const float* g1  = (const float*)d_in[6];
    const float* be1 = (const float*)d_in[7];
    const float* W2  = (const float*)d_in[8];
    const float* b2  = (const float*)d_in[9];
    const float* Ws2 = (const float*)d_in[10];
    const float* bs2 = (const float*)d_in[11];
    const float* g2  = (const float*)d_in[12];
    const float* be2 = (const float*)d_in[13];

    char* ws = (char*)d_ws;
    auto take = [&](size_t bytes) {
        char* p = ws;
        ws += (bytes + 255) & ~(size_t)255;
        return p;
    };
    int*   deg      = (int*)take((size_t)NNODES * 4);
    int*   rowstart = (int*)take((size_t)(NNODES + 1) * 4);
    int*   fill     = (int*)take((size_t)NNODES * 4);
    int*   elist    = (int*)take((size_t)NEDGES * 4);
    float* x1       = (float*)take((size_t)NNODES * 128 * 4);

    hipMemsetAsync(deg, 0, (size_t)NNODES * 4, stream);
    hipMemsetAsync(fill, 0, (size_t)NNODES * 4, stream);

    deg_kernel<<<(NEDGES + 255) / 256, 256, 0, stream>>>(edges, deg, NEDGES);
    scan_kernel<<<1, 1024, 0, stream>>>(deg, rowstart, NNODES);
    fill_kernel<<<(NEDGES + 255) / 256, 256, 0, stream>>>(edges, rowstart, fill, elist, NEDGES);

    layer_kernel<<<NNODES / NPB, 128, 0, stream>>>(
        xemb, rowstart, elist, W1, b1, Ws1, bs1, g1, be1, x1);
    layer_kernel<<<NNODES / NPB, 128, 0, stream>>>(
        x1, rowstart, elist, W2, b2, Ws2, bs2, g2, be2, (float*)d_out);
}